// Round 1
// baseline (302.318 us; speedup 1.0000x reference)
//
#include <hip/hip_runtime.h>
#include <stdint.h>

#define DM 1024      // d_model
#define HEADS 16
#define DHEAD 64
#define BATCH 8
#define SEQ 1024
#define MTOT 8192    // BATCH*SEQ

typedef _Float16 half8 __attribute__((ext_vector_type(8)));
typedef float floatx4 __attribute__((ext_vector_type(4)));

// async global->LDS, 16B per lane. lds dest must be wave-uniform base; HW adds lane*16.
__device__ __forceinline__ void glds16(const void* g, void* l) {
    __builtin_amdgcn_global_load_lds(
        (const __attribute__((address_space(1))) void*)g,
        (__attribute__((address_space(3))) void*)l, 16, 0, 0);
}

// ---------------------------------------------------------------------------
// Convert Q/K/V fp32 -> fp16.  grid (4096, 3) x 256 threads, 8 elems/thread.
__global__ __launch_bounds__(256) void cvt_inputs(
        const float* __restrict__ Q, const float* __restrict__ K,
        const float* __restrict__ V,
        _Float16* __restrict__ qb, _Float16* __restrict__ kb, _Float16* __restrict__ vb) {
    const float* src = blockIdx.y == 0 ? Q : (blockIdx.y == 1 ? K : V);
    _Float16* dst    = blockIdx.y == 0 ? qb : (blockIdx.y == 1 ? kb : vb);
    size_t i = ((size_t)blockIdx.x * 256 + threadIdx.x) * 8;
    float4 a = *(const float4*)(src + i);
    float4 b = *(const float4*)(src + i + 4);
    half8 h;
    h[0] = (_Float16)a.x; h[1] = (_Float16)a.y; h[2] = (_Float16)a.z; h[3] = (_Float16)a.w;
    h[4] = (_Float16)b.x; h[5] = (_Float16)b.y; h[6] = (_Float16)b.z; h[7] = (_Float16)b.w;
    *(half8*)(dst + i) = h;
}

// ---------------------------------------------------------------------------
// Transpose + convert W[K][N] fp32 -> Wt[N][K] fp16.  grid (32,32,3), block (32,8).
__global__ __launch_bounds__(256) void cvt_w(
        const float* __restrict__ Wq, const float* __restrict__ Wk,
        const float* __restrict__ Wv,
        _Float16* __restrict__ wqt, _Float16* __restrict__ wkt, _Float16* __restrict__ wvt) {
    __shared__ float t[32][33];
    int z = blockIdx.z;
    const float* W = z == 0 ? Wq : (z == 1 ? Wk : Wv);
    _Float16* Wt   = z == 0 ? wqt : (z == 1 ? wkt : wvt);
    int k0 = blockIdx.x * 32, n0 = blockIdx.y * 32;
    int tx = threadIdx.x, ty = threadIdx.y;
#pragma unroll
    for (int i = 0; i < 4; i++)
        t[ty + i * 8][tx] = W[(size_t)(k0 + ty + i * 8) * DM + n0 + tx];
    __syncthreads();
#pragma unroll
    for (int i = 0; i < 4; i++)
        Wt[(size_t)(n0 + ty + i * 8) * DM + k0 + tx] = (_Float16)t[tx][ty + i * 8];
}

// ---------------------------------------------------------------------------
// Projection GEMM: C[8192,1024] = A[8192,1024] @ W[1024,1024] + bias.
// grid (64, 8, 3), block 256 (4 waves, 2x2 of 64x64 each).
// z=0: q (scaled by 0.125) -> qh[b][h][s][d]
// z=1: k                   -> kh[b][h][s][d]
// z=2: v                   -> vT[b][h][d][s]   (transposed for PV MFMA)
// LDS tiles 128x64 f16, staged with global_load_lds; XOR-part swizzle folded
// into the global source address so fragment ds_read_b128 are conflict-free.
__global__ __launch_bounds__(256) void proj_gemm(
        const _Float16* __restrict__ qb, const _Float16* __restrict__ kb,
        const _Float16* __restrict__ vb,
        const _Float16* __restrict__ wqt, const _Float16* __restrict__ wkt,
        const _Float16* __restrict__ wvt,
        const float* __restrict__ bq, const float* __restrict__ bk,
        const float* __restrict__ bv,
        _Float16* __restrict__ qh, _Float16* __restrict__ kh, _Float16* __restrict__ vT) {
    __shared__ _Float16 As[128 * 64];
    __shared__ _Float16 Bs[128 * 64];
    int z = blockIdx.z;
    const _Float16* A  = z == 0 ? qb : (z == 1 ? kb : vb);
    const _Float16* Bw = z == 0 ? wqt : (z == 1 ? wkt : wvt);
    const float* bias  = z == 0 ? bq : (z == 1 ? bk : bv);
    int m0 = blockIdx.x * 128, n0 = blockIdx.y * 128;
    int tid = threadIdx.x, wid = tid >> 6, lane = tid & 63;
    int l15 = lane & 15, quad = lane >> 4;
    int wm = wid >> 1, wn = wid & 1;

    floatx4 acc[4][4] = {};

    for (int kb_ = 0; kb_ < 16; kb_++) {
        __syncthreads();
        int k0 = kb_ * 64;
        // stage A and B tiles: 16 issues each, 4 per wave. 8 rows per issue.
        int r = (wid * 4) * 8 + (lane >> 3);            // base row for ii=0
        int pg = (lane & 7) ^ (lane >> 3);              // swizzled 16B part
#pragma unroll
        for (int ii = 0; ii < 4; ii++) {
            int issue = wid * 4 + ii;
            int rr = r + ii * 8;
            glds16(A  + (size_t)(m0 + rr) * DM + k0 + pg * 8, &As[issue * 512]);
            glds16(Bw + (size_t)(n0 + rr) * DM + k0 + pg * 8, &Bs[issue * 512]);
        }
        __syncthreads();
#pragma unroll
        for (int kc = 0; kc < 2; kc++) {
            half8 a[4], b[4];
#pragma unroll
            for (int mt = 0; mt < 4; mt++) {
                int row = wm * 64 + mt * 16 + l15;
                int pl = (kc * 4 + quad) ^ (l15 & 7);
                a[mt] = *(const half8*)&As[row * 64 + pl * 8];
            }
#pragma unroll
            for (int nt = 0; nt < 4; nt++) {
                int row = wn * 64 + nt * 16 + l15;
                int pl = (kc * 4 + quad) ^ (l15 & 7);
                b[nt] = *(const half8*)&Bs[row * 64 + pl * 8];
            }
#pragma unroll
            for (int mt = 0; mt < 4; mt++)
#pragma unroll
                for (int nt = 0; nt < 4; nt++)
                    acc[mt][nt] = __builtin_amdgcn_mfma_f32_16x16x32_f16(
                        a[mt], b[nt], acc[mt][nt], 0, 0, 0);
        }
    }

    float scale = (z == 0) ? 0.125f : 1.0f;   // fold 1/sqrt(d_k) into q
    _Float16* out = (z == 0) ? qh : ((z == 1) ? kh : vT);
#pragma unroll
    for (int nt = 0; nt < 4; nt++) {
        int col = n0 + wn * 64 + nt * 16 + l15;
        float bv_ = bias[col];
        int h = col >> 6, d = col & 63;
#pragma unroll
        for (int mt = 0; mt < 4; mt++) {
#pragma unroll
            for (int r2 = 0; r2 < 4; r2++) {
                int row = m0 + wm * 64 + mt * 16 + quad * 4 + r2;
                int b_ = row >> 10, s = row & 1023;
                float v = (acc[mt][nt][r2] + bv_) * scale;
                size_t off;
                if (z == 2) off = ((size_t)(b_ * HEADS + h)) * 65536 + (size_t)d * 1024 + s;
                else        off = ((size_t)(b_ * HEADS + h)) * 65536 + (size_t)s * 64 + d;
                out[off] = (_Float16)v;
            }
        }
    }
}

// ---------------------------------------------------------------------------
// Attention: per block = 64 q-rows of one (b,h). grid (16, 16, 8), block 256.
// Reference uses raw exp (no max subtraction), so no online rescale needed:
// accumulate num = sum exp(s)*v via MFMA, den = sum exp(s) in registers.
__global__ __launch_bounds__(256) void attn(
        const _Float16* __restrict__ qh, const _Float16* __restrict__ kh,
        const _Float16* __restrict__ vT, float* __restrict__ out) {
    __shared__ _Float16 Qs[4096];
    __shared__ _Float16 Ks[4096];
    __shared__ _Float16 Vs[4096];
    __shared__ _Float16 Ps[4096];   // per-wave 16x64 P tile, A-operand interleaved layout
    int qt = blockIdx.x, h = blockIdx.y, b = blockIdx.z;
    size_t base = ((size_t)(b * HEADS + h)) * 65536;
    int tid = threadIdx.x, wid = tid >> 6, lane = tid & 63;
    int l15 = lane & 15, quad = lane >> 4;
    int rs = lane >> 3;                       // row-within-issue
    int pg = (lane & 7) ^ rs;                 // swizzled 16B part

    // stage Q tile [64][64] once
#pragma unroll
    for (int ii = 0; ii < 2; ii++) {
        int issue = wid * 2 + ii;
        int r = issue * 8 + rs;
        glds16(qh + base + (size_t)(qt * 64 + r) * 64 + pg * 8, &Qs[issue * 512]);
    }
    __syncthreads();
    half8 qf[2];
    {
        int row = wid * 16 + l15;
#pragma unroll
        for (int kc = 0; kc < 2; kc++) {
            int pl = (kc * 4 + quad) ^ (l15 & 7);
            qf[kc] = *(const half8*)&Qs[row * 64 + pl * 8];
        }
    }

    floatx4 oacc[4] = {};
    float rden[4] = {0.f, 0.f, 0.f, 0.f};

    for (int kt = 0; kt < 16; kt++) {
        __syncthreads();
#pragma unroll
        for (int ii = 0; ii < 2; ii++) {
            int issue = wid * 2 + ii;
            int r = issue * 8 + rs;
            glds16(kh + base + (size_t)(kt * 64 + r) * 64 + pg * 8, &Ks[issue * 512]);
            glds16(vT + base + (size_t)r * 1024 + kt * 64 + pg * 8, &Vs[issue * 512]);
        }
        __syncthreads();

        // S = q . k^T  (16 q-rows x 64 keys per wave)
        floatx4 sacc[4] = {};
#pragma unroll
        for (int kc = 0; kc < 2; kc++) {
#pragma unroll
            for (int nt = 0; nt < 4; nt++) {
                int row = nt * 16 + l15;
                int pl = (kc * 4 + quad) ^ (l15 & 7);
                half8 bf = *(const half8*)&Ks[row * 64 + pl * 8];
                sacc[nt] = __builtin_amdgcn_mfma_f32_16x16x32_f16(qf[kc], bf, sacc[nt], 0, 0, 0);
            }
        }
        // exp, denominator partials, and P -> LDS (A-operand interleaved layout)
#pragma unroll
        for (int nt = 0; nt < 4; nt++) {
            int kj = nt * 16 + l15;
            int pbase = wid * 1024 + (kj >> 3) * 128 + (kj & 7);
#pragma unroll
            for (int j = 0; j < 4; j++) {
                float p = __expf(sacc[nt][j]);
                rden[j] += p;
                Ps[pbase + (quad * 4 + j) * 8] = (_Float16)p;
            }
        }
        // O += P @ V
#pragma unroll
        for (int kc = 0; kc < 2; kc++) {
            half8 af = *(const half8*)&Ps[wid * 1024 + (kc * 4 + quad) * 128 + l15 * 8];
#pragma unroll
            for (int nt = 0; nt < 4; nt++) {
                int row = nt * 16 + l15;
                int pl = (kc * 4 + quad) ^ (l15 & 7);
                half8 bf = *(const half8*)&Vs[row * 64 + pl * 8];
                oacc[nt] = __builtin_amdgcn_mfma_f32_16x16x32_f16(af, bf, oacc[nt], 0, 0, 0);
            }
        }
    }

    // reduce denominator across the 16 lanes sharing a row group
#pragma unroll
    for (int j = 0; j < 4; j++) {
        float d = rden[j];
        d += __shfl_xor(d, 1, 64);
        d += __shfl_xor(d, 2, 64);
        d += __shfl_xor(d, 4, 64);
        d += __shfl_xor(d, 8, 64);
        rden[j] = 1.0f / (d + 1e-8f);
    }
#pragma unroll
    for (int nt = 0; nt < 4; nt++) {
        int col = h * 64 + nt * 16 + l15;
#pragma unroll
        for (int j = 0; j < 4; j++) {
            int s = qt * 64 + wid * 16 + quad * 4 + j;
            out[((size_t)(b * SEQ + s)) * 1024 + col] = oacc[nt][j] * rden[j];
        }
    }
}

// ---------------------------------------------------------------------------
extern "C" void kernel_launch(void* const* d_in, const int* in_sizes, int n_in,
                              void* d_out, int out_size, void* d_ws, size_t ws_size,
                              hipStream_t stream) {
    const float* Q  = (const float*)d_in[0];
    const float* K  = (const float*)d_in[1];
    const float* V  = (const float*)d_in[2];
    const float* Wq = (const float*)d_in[3];
    const float* bq = (const float*)d_in[4];
    const float* Wk = (const float*)d_in[5];
    const float* bk = (const float*)d_in[6];
    const float* Wv = (const float*)d_in[7];
    const float* bv = (const float*)d_in[8];
    float* out = (float*)d_out;

    char* ws = (char*)d_ws;
    const size_t TEN = (size_t)MTOT * DM * sizeof(_Float16);   // 16 MiB
    _Float16* qb  = (_Float16*)(ws);
    _Float16* kb  = (_Float16*)(ws + TEN);
    _Float16* vb  = (_Float16*)(ws + 2 * TEN);
    _Float16* qh  = (_Float16*)(ws + 3 * TEN);
    _Float16* kh  = (_Float16*)(ws + 4 * TEN);
    _Float16* vT  = (_Float16*)(ws + 5 * TEN);
    const size_t WTN = (size_t)DM * DM * sizeof(_Float16);     // 2 MiB
    _Float16* wqt = (_Float16*)(ws + 6 * TEN);
    _Float16* wkt = (_Float16*)(ws + 6 * TEN + WTN);
    _Float16* wvt = (_Float16*)(ws + 6 * TEN + 2 * WTN);

    cvt_inputs<<<dim3(4096, 3), 256, 0, stream>>>(Q, K, V, qb, kb, vb);
    cvt_w<<<dim3(32, 32, 3), dim3(32, 8), 0, stream>>>(Wq, Wk, Wv, wqt, wkt, wvt);
    proj_gemm<<<dim3(64, 8, 3), 256, 0, stream>>>(qb, kb, vb, wqt, wkt, wvt,
                                                  bq, bk, bv, qh, kh, vT);
    attn<<<dim3(16, 16, 8), 256, 0, stream>>>(qh, kh, vT, out);
}

// Round 2
// 280.790 us; speedup vs baseline: 1.0767x; 1.0767x over previous
//
#include <hip/hip_runtime.h>
#include <stdint.h>

#define DM 1024      // d_model
#define HEADS 16
#define BATCH 8
#define SEQ 1024
#define MTOT 8192    // BATCH*SEQ

typedef _Float16 half8 __attribute__((ext_vector_type(8)));
typedef _Float16 half4 __attribute__((ext_vector_type(4)));
typedef float floatx4 __attribute__((ext_vector_type(4)));

// async global->LDS, 16B per lane. lds dest must be wave-uniform base; HW adds lane*16.
__device__ __forceinline__ void glds16(const void* g, void* l) {
    __builtin_amdgcn_global_load_lds(
        (const __attribute__((address_space(1))) void*)g,
        (__attribute__((address_space(3))) void*)l, 16, 0, 0);
}

// ---------------------------------------------------------------------------
// Convert Q/K/V fp32 -> fp16.  grid (4096, 3) x 256 threads, 8 elems/thread.
__global__ __launch_bounds__(256) void cvt_inputs(
        const float* __restrict__ Q, const float* __restrict__ K,
        const float* __restrict__ V,
        _Float16* __restrict__ qb, _Float16* __restrict__ kb, _Float16* __restrict__ vb) {
    const float* src = blockIdx.y == 0 ? Q : (blockIdx.y == 1 ? K : V);
    _Float16* dst    = blockIdx.y == 0 ? qb : (blockIdx.y == 1 ? kb : vb);
    size_t i = ((size_t)blockIdx.x * 256 + threadIdx.x) * 8;
    float4 a = *(const float4*)(src + i);
    float4 b = *(const float4*)(src + i + 4);
    half8 h;
    h[0] = (_Float16)a.x; h[1] = (_Float16)a.y; h[2] = (_Float16)a.z; h[3] = (_Float16)a.w;
    h[4] = (_Float16)b.x; h[5] = (_Float16)b.y; h[6] = (_Float16)b.z; h[7] = (_Float16)b.w;
    *(half8*)(dst + i) = h;
}

// ---------------------------------------------------------------------------
// Transpose + convert W[K][N] fp32 -> Wt[N][K] fp16.  grid (32,32,3), block (32,8).
__global__ __launch_bounds__(256) void cvt_w(
        const float* __restrict__ Wq, const float* __restrict__ Wk,
        const float* __restrict__ Wv,
        _Float16* __restrict__ wqt, _Float16* __restrict__ wkt, _Float16* __restrict__ wvt) {
    __shared__ float t[32][33];
    int z = blockIdx.z;
    const float* W = z == 0 ? Wq : (z == 1 ? Wk : Wv);
    _Float16* Wt   = z == 0 ? wqt : (z == 1 ? wkt : wvt);
    int k0 = blockIdx.x * 32, n0 = blockIdx.y * 32;
    int tx = threadIdx.x, ty = threadIdx.y;
#pragma unroll
    for (int i = 0; i < 4; i++)
        t[ty + i * 8][tx] = W[(size_t)(k0 + ty + i * 8) * DM + n0 + tx];
    __syncthreads();
#pragma unroll
    for (int i = 0; i < 4; i++)
        Wt[(size_t)(n0 + ty + i * 8) * DM + k0 + tx] = (_Float16)t[tx][ty + i * 8];
}

// ---------------------------------------------------------------------------
// Projection GEMM: C[8192,1024] = A[8192,1024] @ W[1024,1024] + bias.
// grid (64, 8, 3), block 256 (4 waves, 2x2 of 64x64 each).
// z<2: MFMA operand order swapped (A-op = W-frag) so accumulator rows = d
//      (consecutive) -> packed 8B stores to [b][h][s][d].
// z=2: original order, accumulator rows = s -> packed 8B stores to vT [b][h][d][s].
__global__ __launch_bounds__(256) void proj_gemm(
        const _Float16* __restrict__ qb, const _Float16* __restrict__ kb,
        const _Float16* __restrict__ vb,
        const _Float16* __restrict__ wqt, const _Float16* __restrict__ wkt,
        const _Float16* __restrict__ wvt,
        const float* __restrict__ bq, const float* __restrict__ bk,
        const float* __restrict__ bv,
        _Float16* __restrict__ qh, _Float16* __restrict__ kh, _Float16* __restrict__ vT) {
    __shared__ _Float16 As[128 * 64];
    __shared__ _Float16 Bs[128 * 64];
    int z = blockIdx.z;
    const _Float16* A  = z == 0 ? qb : (z == 1 ? kb : vb);
    const _Float16* Bw = z == 0 ? wqt : (z == 1 ? wkt : wvt);
    const float* bias  = z == 0 ? bq : (z == 1 ? bk : bv);
    int m0 = blockIdx.x * 128, n0 = blockIdx.y * 128;
    int tid = threadIdx.x, wid = tid >> 6, lane = tid & 63;
    int l15 = lane & 15, quad = lane >> 4;
    int wm = wid >> 1, wn = wid & 1;
    bool swapped = (z < 2);

    floatx4 acc[4][4] = {};

    for (int kb_ = 0; kb_ < 16; kb_++) {
        __syncthreads();
        int k0 = kb_ * 64;
        int r = (wid * 4) * 8 + (lane >> 3);
        int pg = (lane & 7) ^ (lane >> 3);
#pragma unroll
        for (int ii = 0; ii < 4; ii++) {
            int issue = wid * 4 + ii;
            int rr = r + ii * 8;
            glds16(A  + (size_t)(m0 + rr) * DM + k0 + pg * 8, &As[issue * 512]);
            glds16(Bw + (size_t)(n0 + rr) * DM + k0 + pg * 8, &Bs[issue * 512]);
        }
        __syncthreads();
#pragma unroll
        for (int kc = 0; kc < 2; kc++) {
            half8 a[4], b[4];
#pragma unroll
            for (int mt = 0; mt < 4; mt++) {
                int row = wm * 64 + mt * 16 + l15;
                int pl = (kc * 4 + quad) ^ (l15 & 7);
                a[mt] = *(const half8*)&As[row * 64 + pl * 8];
            }
#pragma unroll
            for (int nt = 0; nt < 4; nt++) {
                int row = wn * 64 + nt * 16 + l15;
                int pl = (kc * 4 + quad) ^ (l15 & 7);
                b[nt] = *(const half8*)&Bs[row * 64 + pl * 8];
            }
            if (swapped) {
#pragma unroll
                for (int mt = 0; mt < 4; mt++)
#pragma unroll
                    for (int nt = 0; nt < 4; nt++)
                        acc[mt][nt] = __builtin_amdgcn_mfma_f32_16x16x32_f16(
                            b[nt], a[mt], acc[mt][nt], 0, 0, 0);
            } else {
#pragma unroll
                for (int mt = 0; mt < 4; mt++)
#pragma unroll
                    for (int nt = 0; nt < 4; nt++)
                        acc[mt][nt] = __builtin_amdgcn_mfma_f32_16x16x32_f16(
                            a[mt], b[nt], acc[mt][nt], 0, 0, 0);
            }
        }
    }

    if (swapped) {
        // acc[mt][nt]: element (s, d): s = m0+wm*64+mt*16+l15 (per-lane col),
        //                              d = n0+wn*64+nt*16+quad*4+r (rows, consecutive)
        float sc = (z == 0) ? 0.125f : 1.0f;
        _Float16* out = (z == 0) ? qh : kh;
#pragma unroll
        for (int nt = 0; nt < 4; nt++) {
            int d0 = n0 + wn * 64 + nt * 16 + quad * 4;
            int hh = d0 >> 6, dd = d0 & 63;
            floatx4 b4 = *(const floatx4*)&bias[d0];
#pragma unroll
            for (int mt = 0; mt < 4; mt++) {
                int s = m0 + wm * 64 + mt * 16 + l15;
                int b_ = s >> 10, ss = s & 1023;
                size_t off = ((size_t)(b_ * HEADS + hh)) * 65536 + (size_t)ss * 64 + dd;
                half4 hv;
#pragma unroll
                for (int r = 0; r < 4; r++)
                    hv[r] = (_Float16)((acc[mt][nt][r] + b4[r]) * sc);
                *(half4*)&out[off] = hv;
            }
        }
    } else {
        // acc[mt][nt]: element (s, d): d = n0+wn*64+nt*16+l15 (per-lane col),
        //                              s = m0+wm*64+mt*16+quad*4+r (rows, consecutive)
#pragma unroll
        for (int nt = 0; nt < 4; nt++) {
            int d = n0 + wn * 64 + nt * 16 + l15;
            int hh = d >> 6, dd = d & 63;
            float bv_ = bias[d];
#pragma unroll
            for (int mt = 0; mt < 4; mt++) {
                int s0 = m0 + wm * 64 + mt * 16 + quad * 4;
                int b_ = s0 >> 10, ss = s0 & 1023;
                size_t off = ((size_t)(b_ * HEADS + hh)) * 65536 + (size_t)dd * 1024 + ss;
                half4 hv;
#pragma unroll
                for (int r = 0; r < 4; r++)
                    hv[r] = (_Float16)(acc[mt][nt][r] + bv_);
                *(half4*)&vT[off] = hv;
            }
        }
    }
}

// ---------------------------------------------------------------------------
// Attention: one block = 256 q-rows of one (b,h); 64 q-rows per wave.
// grid (4, 16, 8), block 256. S^T = K*Q^T so P-writes are packed ds_write_b64;
// P lives in the dead Q-tile LDS region (per-wave 64x64 tile).
// LDS: Ks 8KB + Vs 8KB + QP 32KB = 48 KB.
__global__ __launch_bounds__(256) void attn(
        const _Float16* __restrict__ qh, const _Float16* __restrict__ kh,
        const _Float16* __restrict__ vT, float* __restrict__ out) {
    __shared__ _Float16 Ks[4096];
    __shared__ _Float16 Vs[4096];
    __shared__ _Float16 QP[16384];
    int qt = blockIdx.x, h = blockIdx.y, b = blockIdx.z;
    size_t base = ((size_t)(b * HEADS + h)) * 65536;
    int tid = threadIdx.x, wid = tid >> 6, lane = tid & 63;
    int l15 = lane & 15, quad = lane >> 4;
    int rs = lane >> 3;
    int pg = (lane & 7) ^ rs;

    // stage Q tile [256][64]
#pragma unroll
    for (int ii = 0; ii < 8; ii++) {
        int issue = wid * 8 + ii;
        int r = issue * 8 + rs;
        glds16(qh + base + (size_t)(qt * 256 + r) * 64 + pg * 8, &QP[issue * 512]);
    }
    __syncthreads();
    half8 qf[4][2];
#pragma unroll
    for (int mt = 0; mt < 4; mt++)
#pragma unroll
        for (int kc = 0; kc < 2; kc++) {
            int row = wid * 64 + mt * 16 + l15;
            int pl = (kc * 4 + quad) ^ (l15 & 7);
            qf[mt][kc] = *(const half8*)&QP[row * 64 + pl * 8];
        }
    __syncthreads();   // all q-frag reads done before P overwrites the region

    floatx4 oacc[4][4] = {};
    float rden[4] = {0.f, 0.f, 0.f, 0.f};
    _Float16* Pw = &QP[wid * 4096];   // per-wave 64q x 64k P tile
                                      // layout: (k>>3)*512 + q*8 + (k&7)

    for (int kt = 0; kt < 16; kt++) {
        __syncthreads();
#pragma unroll
        for (int ii = 0; ii < 2; ii++) {
            int issue = wid * 2 + ii;
            int r = issue * 8 + rs;
            glds16(kh + base + (size_t)(kt * 64 + r) * 64 + pg * 8, &Ks[issue * 512]);
            glds16(vT + base + (size_t)r * 1024 + kt * 64 + pg * 8, &Vs[issue * 512]);
        }
        __syncthreads();

#pragma unroll
        for (int hf = 0; hf < 2; hf++) {
            // S^T = K * Q^T for 32 keys: D rows = key (consecutive), cols = query
            floatx4 sacc[2][4] = {};
#pragma unroll
            for (int kc = 0; kc < 2; kc++) {
                half8 kf[2];
#pragma unroll
                for (int kn2 = 0; kn2 < 2; kn2++) {
                    int kn = hf * 2 + kn2;
                    int pl = (kc * 4 + quad) ^ (l15 & 7);
                    kf[kn2] = *(const half8*)&Ks[(kn * 16 + l15) * 64 + pl * 8];
                }
#pragma unroll
                for (int kn2 = 0; kn2 < 2; kn2++)
#pragma unroll
                    for (int mt = 0; mt < 4; mt++)
                        sacc[kn2][mt] = __builtin_amdgcn_mfma_f32_16x16x32_f16(
                            kf[kn2], qf[mt][kc], sacc[kn2][mt], 0, 0, 0);
            }
            // exp + packed P write: element (key kn*16+quad*4+r, query mt*16+l15)
#pragma unroll
            for (int kn2 = 0; kn2 < 2; kn2++) {
                int kn = hf * 2 + kn2;
#pragma unroll
                for (int mt = 0; mt < 4; mt++) {
                    half4 ph;
#pragma unroll
                    for (int r = 0; r < 4; r++) {
                        float p = __expf(sacc[kn2][mt][r]);
                        rden[mt] += p;
                        ph[r] = (_Float16)p;
                    }
                    *(half4*)&Pw[(kn * 2 + (quad >> 1)) * 512 + (mt * 16 + l15) * 8 +
                                 (quad & 1) * 4] = ph;
                }
            }
            // O += P * V for these 32 keys
            half8 af[4], vf[4];
#pragma unroll
            for (int mt = 0; mt < 4; mt++)
                af[mt] = *(const half8*)&Pw[(hf * 4 + quad) * 512 + (mt * 16 + l15) * 8];
#pragma unroll
            for (int dn = 0; dn < 4; dn++) {
                int pl = (hf * 4 + quad) ^ (l15 & 7);
                vf[dn] = *(const half8*)&Vs[(dn * 16 + l15) * 64 + pl * 8];
            }
#pragma unroll
            for (int mt = 0; mt < 4; mt++)
#pragma unroll
                for (int dn = 0; dn < 4; dn++)
                    oacc[mt][dn] = __builtin_amdgcn_mfma_f32_16x16x32_f16(
                        af[mt], vf[dn], oacc[mt][dn], 0, 0, 0);
        }
    }

    // denominator: reduce across quads (each lane summed keys = quad*4+r pattern)
#pragma unroll
    for (int mt = 0; mt < 4; mt++) {
        float d = rden[mt];
        d += __shfl_xor(d, 16, 64);
        d += __shfl_xor(d, 32, 64);
        rden[mt] = 1.0f / (d + 1e-8f);
    }
    // oacc[mt][dn]: rows = q (mt*16+quad*4+r), cols = d (dn*16+l15)
#pragma unroll
    for (int mt = 0; mt < 4; mt++) {
#pragma unroll
        for (int r = 0; r < 4; r++) {
            float dinv = __shfl(rden[mt], quad * 4 + r, 16);
            int s = qt * 256 + wid * 64 + mt * 16 + quad * 4 + r;
#pragma unroll
            for (int dn = 0; dn < 4; dn++) {
                int col = h * 64 + dn * 16 + l15;
                out[((size_t)(b * SEQ + s)) * 1024 + col] = oacc[mt][dn][r] * dinv;
            }
        }
    }
}

// ---------------------------------------------------------------------------
extern "C" void kernel_launch(void* const* d_in, const int* in_sizes, int n_in,
                              void* d_out, int out_size, void* d_ws, size_t ws_size,
                              hipStream_t stream) {
    const float* Q  = (const float*)d_in[0];
    const float* K  = (const float*)d_in[1];
    const float* V  = (const float*)d_in[2];
    const float* Wq = (const float*)d_in[3];
    const float* bq = (const float*)d_in[4];
    const float* Wk = (const float*)d_in[5];
    const float* bk = (const float*)d_in[6];
    const float* Wv = (const float*)d_in[7];
    const float* bv = (const float*)d_in[8];
    float* out = (float*)d_out;

    char* ws = (char*)d_ws;
    const size_t TEN = (size_t)MTOT * DM * sizeof(_Float16);   // 16 MiB
    _Float16* qb  = (_Float16*)(ws);
    _Float16* kb  = (_Float16*)(ws + TEN);
    _Float16* vb  = (_Float16*)(ws + 2 * TEN);
    _Float16* qh  = (_Float16*)(ws + 3 * TEN);
    _Float16* kh  = (_Float16*)(ws + 4 * TEN);
    _Float16* vT  = (_Float16*)(ws + 5 * TEN);
    const size_t WTN = (size_t)DM * DM * sizeof(_Float16);     // 2 MiB
    _Float16* wqt = (_Float16*)(ws + 6 * TEN);
    _Float16* wkt = (_Float16*)(ws + 6 * TEN + WTN);
    _Float16* wvt = (_Float16*)(ws + 6 * TEN + 2 * WTN);

    cvt_inputs<<<dim3(4096, 3), 256, 0, stream>>>(Q, K, V, qb, kb, vb);
    cvt_w<<<dim3(32, 32, 3), dim3(32, 8), 0, stream>>>(Wq, Wk, Wv, wqt, wkt, wvt);
    proj_gemm<<<dim3(64, 8, 3), 256, 0, stream>>>(qb, kb, vb, wqt, wkt, wvt,
                                                  bq, bk, bv, qh, kh, vT);
    attn<<<dim3(4, 16, 8), 256, 0, stream>>>(qh, kh, vT, out);
}